// Round 13
// baseline (157.560 us; speedup 1.0000x reference)
//
#include <hip/hip_runtime.h>

#define NNODES 50000
#define NEDGES 200000
#define DDIM 512

typedef __attribute__((ext_vector_type(8))) short bf16x8;
typedef __attribute__((ext_vector_type(4))) float f32x4;

static __device__ __forceinline__ unsigned short f2bf(float f) {
  unsigned u = __float_as_uint(f);
  unsigned r = (u + 0x7fffu + ((u >> 16) & 1u)) >> 16;  // RNE
  return (unsigned short)r;
}

static __device__ __forceinline__ void gload_lds16(const void* g, void* l) {
  __builtin_amdgcn_global_load_lds(
      (const __attribute__((address_space(1))) unsigned int*)g,
      (__attribute__((address_space(3))) unsigned int*)l, 16, 0, 0);
}

// 8 fp32 -> bf16x8 via hardware v_cvt_pk_bf16_f32 (RNE, matches f2bf)
static __device__ __forceinline__ bf16x8 cvt_frag(f32x4 lo, f32x4 hi) {
  union { bf16x8 v; unsigned u[4]; } r;
  asm("v_cvt_pk_bf16_f32 %0, %1, %2" : "=v"(r.u[0]) : "v"(lo.x), "v"(lo.y));
  asm("v_cvt_pk_bf16_f32 %0, %1, %2" : "=v"(r.u[1]) : "v"(lo.z), "v"(lo.w));
  asm("v_cvt_pk_bf16_f32 %0, %1, %2" : "=v"(r.u[2]) : "v"(hi.x), "v"(hi.y));
  asm("v_cvt_pk_bf16_f32 %0, %1, %2" : "=v"(r.u[3]) : "v"(hi.z), "v"(hi.w));
  return r.v;
}

// ---------------------------------------------------------------------------
// Wt[n][k] = bf16(W[k][n])  (512x512 transpose via LDS) + zero deg[]
// ---------------------------------------------------------------------------
__global__ __launch_bounds__(256) void cvt_wt_kernel(
    const float* __restrict__ W, unsigned short* __restrict__ Wt,
    int* __restrict__ deg) {
  const int gid = (blockIdx.x + blockIdx.y * gridDim.x) * 256 + threadIdx.x;
  if (gid < NNODES) deg[gid] = 0;

  __shared__ float t[32][33];
  const int n0 = blockIdx.x * 32, k0 = blockIdx.y * 32;
  const int tx = threadIdx.x & 31, ty = threadIdx.x >> 5;  // ty 0..7
  for (int r = ty; r < 32; r += 8)
    t[r][tx] = W[(size_t)(k0 + r) * DDIM + n0 + tx];
  __syncthreads();
  for (int r = ty; r < 32; r += 8)
    Wt[(size_t)(n0 + r) * DDIM + k0 + tx] = f2bf(t[tx][r]);
}

// ---------------------------------------------------------------------------
// MFMA GEMM: C_bf16[M,512] = bf16(A_f32[M,512]) @ Wt_bf16[512,512]^T + bias
// A-SLAB PERSIST structure: tile 48 rows x 256 cols, 4 waves (1M x 4N),
// K=512 fully resident in LDS as bf16.
//   Prologue: block reg-loads its 48x512 fp32 A-slab (coalesced 2KB/row),
//   cvt_pk -> bf16, ds_write with chunk-XOR swizzle (c' = c ^ (row&7)) —
//   reg-staged writes allow real swizzle => 2-way conflicts = free.
//   K-loop: stages ONLY B (2-phase dbuf, proven 0-conflict path), 16 steps,
//   12 MFMA/wave/step, A frags read from slab.
// LDS 80KB => 2 blocks/CU: one block's prologue overlaps the other's K-loop.
// No cvt_h pass needed; A read 2x total (one per N-tile).
// ---------------------------------------------------------------------------
__global__ __launch_bounds__(256) void gemm_mfma_kernel(
    const float* __restrict__ A, const unsigned short* __restrict__ Bt,
    const float* __restrict__ bias, unsigned short* __restrict__ C, int M) {
  __shared__ unsigned short Aslab[48 * 512];     // 48 KB persistent bf16 A
  __shared__ unsigned short Bs[2][256 * 32];     // 2 x 16 KB bf16 B tiles
  const int tid = threadIdx.x;
  const int wid = tid >> 6, lane = tid & 63;

  // bijective XCD-chunked remap (8 XCDs)
  const int nwg = gridDim.x;
  const int q = nwg >> 3, rr8 = nwg & 7;
  const int x = blockIdx.x & 7, idx = blockIdx.x >> 3;
  const int wg = x * q + min(x, rr8) + idx;

  const int mt = wg >> 1, nt = wg & 1;
  const int bm = mt * 48, bn = nt * 256;

  f32x4 acc[3][4] = {};

  const int l16 = lane & 15, lk = lane >> 4;
  const int lke = lk ^ ((l16 >> 1) & 3);  // B swizzled read k-group

  // ---- Prologue: stage 48x512 fp32 -> bf16 swizzled slab
  {
    const int prow = tid >> 4;          // 0..15 (per pass)
    const int pcol = (tid & 15) * 32;   // 32 floats per thread per pass
#pragma unroll
    for (int rr = 0; rr < 3; ++rr) {
      const int row = rr * 16 + prow;
      const int grow = min(bm + row, M - 1);
      const float* src = A + (size_t)grow * DDIM + pcol;
      f32x4 v[8];
#pragma unroll
      for (int qv = 0; qv < 8; ++qv) v[qv] = ((const f32x4*)src)[qv];
#pragma unroll
      for (int q2 = 0; q2 < 4; ++q2) {
        const bf16x8 w = cvt_frag(v[2 * q2], v[2 * q2 + 1]);
        const int c = (pcol >> 3) + q2;           // global chunk 0..63
        *(bf16x8*)&Aslab[row * 512 + (c ^ (row & 7)) * 8] = w;
      }
    }
  }

  // ---- B staging geometry: 1024 16B-slots per 16KB tile, 4 per thread
  const unsigned short* pb[4];
  int dstOff[4];
#pragma unroll
  for (int p = 0; p < 4; ++p) {
    const int sidx = p * 256 + tid;
    const int brow = sidx >> 2;                       // 0..255
    const int cg = (sidx & 3) ^ ((brow >> 1) & 3);    // swizzled source grp
    pb[p] = Bt + (size_t)(bn + brow) * DDIM + cg * 8;
    dstOff[p] = sidx * 8;                             // ushort units (linear)
  }

#define BSTAGE(buf, k0)                                       \
  do {                                                        \
    gload_lds16(pb[0] + (k0), &Bs[buf][(0 * 256 + wid * 64) * 8]); \
    gload_lds16(pb[1] + (k0), &Bs[buf][(1 * 256 + wid * 64) * 8]); \
    gload_lds16(pb[2] + (k0), &Bs[buf][(2 * 256 + wid * 64) * 8]); \
    gload_lds16(pb[3] + (k0), &Bs[buf][(3 * 256 + wid * 64) * 8]); \
  } while (0)

#define COMPUTE(buf, step)                                                    \
  do {                                                                        \
    bf16x8 af[3], bfr[4];                                                     \
    _Pragma("unroll") for (int i = 0; i < 3; ++i) {                           \
      const int row = i * 16 + l16;                                           \
      const int c = (step) * 4 + lk;                                          \
      af[i] = *(const bf16x8*)&Aslab[row * 512 + (c ^ (row & 7)) * 8];        \
    }                                                                         \
    _Pragma("unroll") for (int j = 0; j < 4; ++j)                             \
      bfr[j] = *(const bf16x8*)&Bs[buf][(wid * 64 + j * 16 + l16) * 32 + lke * 8]; \
    _Pragma("unroll") for (int i = 0; i < 3; ++i)                             \
        _Pragma("unroll") for (int j = 0; j < 4; ++j)                         \
            acc[i][j] = __builtin_amdgcn_mfma_f32_16x16x32_bf16(              \
                af[i], bfr[j], acc[i][j], 0, 0, 0);                           \
  } while (0)

  BSTAGE(0, 0);
  __syncthreads();  // slab written + B tile 0 ready
#pragma unroll 2
  for (int t = 0; t < 15; ++t) {
    const int cur = t & 1;
    BSTAGE(cur ^ 1, (t + 1) * 32);  // prefetch next B tile
    COMPUTE(cur, t);
    __syncthreads();
  }
  COMPUTE(1, 15);
  __syncthreads();  // Bs about to be reused as epilogue scratch

  // ---- Epilogue: per-wave 48x64 bf16 tile staged in Bs, coalesced stores.
  unsigned short* cl = &Bs[0][0] + wid * 3072;  // 48*64 ushorts per wave
#pragma unroll
  for (int j = 0; j < 4; ++j) {
    const float bv = bias[bn + wid * 64 + j * 16 + l16];
#pragma unroll
    for (int i = 0; i < 3; ++i)
#pragma unroll
      for (int qq = 0; qq < 4; ++qq)
        cl[(i * 16 + lk * 4 + qq) * 64 + j * 16 + l16] =
            f2bf(acc[i][j][qq] + bv);
  }
  __syncthreads();
#pragma unroll
  for (int pass = 0; pass < 6; ++pass) {
    const int rt = pass * 8 + (lane >> 3);   // row in 48x64 tile
    const int c0 = (lane & 7) * 8;           // col (8 bf16 = 16B per lane)
    const int grow = bm + rt;
    if (grow < M) {
      const uint4 v = *(const uint4*)&cl[rt * 64 + c0];
      *(uint4*)&C[(size_t)grow * DDIM + bn + wid * 64 + c0] = v;
    }
  }
#undef BSTAGE
#undef COMPUTE
}

// ---------------------------------------------------------------------------
// CSR build: histogram of dst
// ---------------------------------------------------------------------------
__global__ __launch_bounds__(256) void hist_kernel(const int* __restrict__ dst,
                                                   int* __restrict__ deg, int E) {
  const int e = blockIdx.x * 256 + threadIdx.x;
  if (e < E) atomicAdd(&deg[dst[e]], 1);
}

// ---------------------------------------------------------------------------
// Parallel 3-kernel exclusive scan over deg[0..n) -> off[0..n], cur[0..n)
// ---------------------------------------------------------------------------
__global__ __launch_bounds__(256) void chunk_sum_kernel(
    const int* __restrict__ deg, int* __restrict__ part, int n) {
  const int base = blockIdx.x * 1024;
  int v = 0;
  for (int i = threadIdx.x; i < 1024; i += 256) {
    const int idx = base + i;
    v += (idx < n) ? deg[idx] : 0;
  }
#pragma unroll
  for (int s = 32; s; s >>= 1) v += __shfl_down(v, s, 64);
  __shared__ int ws[4];
  if ((threadIdx.x & 63) == 0) ws[threadIdx.x >> 6] = v;
  __syncthreads();
  if (threadIdx.x == 0) part[blockIdx.x] = ws[0] + ws[1] + ws[2] + ws[3];
}

__global__ void scan_part_kernel(int* __restrict__ part, int nb) {
  const int lane = threadIdx.x & 63;
  int v = (lane < nb) ? part[lane] : 0;
  int incl = v;
#pragma unroll
  for (int s = 1; s < 64; s <<= 1) {
    int t = __shfl_up(incl, s, 64);
    if (lane >= s) incl += t;
  }
  if (lane < nb) part[lane] = incl - v;  // exclusive
}

__global__ __launch_bounds__(1024) void chunk_scan_kernel(
    const int* __restrict__ deg, const int* __restrict__ part,
    int* __restrict__ off, int* __restrict__ cur, int n) {
  __shared__ int wsum[16];
  const int tid = threadIdx.x, lane = tid & 63, wid = tid >> 6;
  const int i = blockIdx.x * 1024 + tid;
  const int v = (i < n) ? deg[i] : 0;
  int incl = v;
#pragma unroll
  for (int s = 1; s < 64; s <<= 1) {
    int t = __shfl_up(incl, s, 64);
    if (lane >= s) incl += t;
  }
  if (lane == 63) wsum[wid] = incl;
  __syncthreads();
  if (wid == 0 && lane < 16) {
    int wv = wsum[lane];
#pragma unroll
    for (int s = 1; s < 16; s <<= 1) {
      int t = __shfl_up(wv, s, 16);
      if (lane >= s) wv += t;
    }
    wsum[lane] = wv;
  }
  __syncthreads();
  const int add = part[blockIdx.x] + ((wid > 0) ? wsum[wid - 1] : 0);
  if (i < n) {
    off[i + 1] = add + incl;
    cur[i] = add + incl - v;
  }
  if (i == 0) off[0] = 0;
}

// ---------------------------------------------------------------------------
// CSR fill: slot per edge via per-dst cursor; pack (src, weight) as uint2.
// ---------------------------------------------------------------------------
__global__ __launch_bounds__(256) void fill_kernel(
    const int* __restrict__ src, const int* __restrict__ dst,
    const float* __restrict__ ew, int* __restrict__ cur,
    uint2* __restrict__ epair, int E) {
  const int e = blockIdx.x * 256 + threadIdx.x;
  if (e >= E) return;
  const int p = atomicAdd(&cur[dst[e]], 1);
  epair[p] = make_uint2((unsigned)src[e], __float_as_uint(ew[e]));
}

// ---------------------------------------------------------------------------
// Gather: one wave per node; 4-deep edge unroll; mean + relu; nontemporal
// row write.
// ---------------------------------------------------------------------------
__global__ __launch_bounds__(256) void gather_kernel(
    const unsigned short* __restrict__ hp, const int* __restrict__ off,
    const uint2* __restrict__ epair, float* __restrict__ out, int n) {
  const int node = blockIdx.x * 4 + (threadIdx.x >> 6);
  if (node >= n) return;
  const int lane = threadIdx.x & 63;
  const int beg = off[node], end = off[node + 1];

  float acc[8] = {0.f, 0.f, 0.f, 0.f, 0.f, 0.f, 0.f, 0.f};
  int p = beg;
  for (; p + 4 <= end; p += 4) {
    uint2 e[4];
    uint4 u[4];
#pragma unroll
    for (int m = 0; m < 4; ++m) e[m] = epair[p + m];
#pragma unroll
    for (int m = 0; m < 4; ++m)
      u[m] = *(const uint4*)(hp + (size_t)e[m].x * DDIM + lane * 8);
#pragma unroll
    for (int m = 0; m < 4; ++m) {
      const float w = __uint_as_float(e[m].y);
      const unsigned a[4] = {u[m].x, u[m].y, u[m].z, u[m].w};
#pragma unroll
      for (int qv = 0; qv < 4; ++qv) {
        acc[2 * qv + 0] += w * __uint_as_float(a[qv] << 16);
        acc[2 * qv + 1] += w * __uint_as_float(a[qv] & 0xffff0000u);
      }
    }
  }
  for (; p < end; ++p) {
    const uint2 e0 = epair[p];
    const float w0 = __uint_as_float(e0.y);
    const uint4 u0 = *(const uint4*)(hp + (size_t)e0.x * DDIM + lane * 8);
    const unsigned a0[4] = {u0.x, u0.y, u0.z, u0.w};
#pragma unroll
    for (int qv = 0; qv < 4; ++qv) {
      acc[2 * qv + 0] += w0 * __uint_as_float(a0[qv] << 16);
      acc[2 * qv + 1] += w0 * __uint_as_float(a0[qv] & 0xffff0000u);
    }
  }

  const float inv = 1.0f / fmaxf((float)(end - beg), 1.0f);
  f32x4 o0, o1;
  o0.x = fmaxf(acc[0] * inv, 0.f);
  o0.y = fmaxf(acc[1] * inv, 0.f);
  o0.z = fmaxf(acc[2] * inv, 0.f);
  o0.w = fmaxf(acc[3] * inv, 0.f);
  o1.x = fmaxf(acc[4] * inv, 0.f);
  o1.y = fmaxf(acc[5] * inv, 0.f);
  o1.z = fmaxf(acc[6] * inv, 0.f);
  o1.w = fmaxf(acc[7] * inv, 0.f);
  float* orow = out + (size_t)node * DDIM + lane * 8;
  __builtin_nontemporal_store(o0, (f32x4*)(orow + 0));
  __builtin_nontemporal_store(o1, (f32x4*)(orow + 4));
}

extern "C" void kernel_launch(void* const* d_in, const int* in_sizes, int n_in,
                              void* d_out, int out_size, void* d_ws, size_t ws_size,
                              hipStream_t stream) {
  const float* h  = (const float*)d_in[0];
  const float* W  = (const float*)d_in[1];
  const float* b  = (const float*)d_in[2];
  const float* ew = (const float*)d_in[3];
  const int* src  = (const int*)d_in[4];
  const int* dst  = (const int*)d_in[5];
  float* out = (float*)d_out;

  // Workspace: hp (bf16 h_proj), Wt, CSR arrays
  char* ws = (char*)d_ws;
  size_t o = 0;
  auto alloc = [&](size_t bytes) {
    char* p = ws + o;
    o += (bytes + 255) & ~(size_t)255;
    return p;
  };
  unsigned short* hp = (unsigned short*)alloc((size_t)NNODES * DDIM * 2);  // 51.2 MB
  unsigned short* Wt = (unsigned short*)alloc((size_t)DDIM * DDIM * 2);    // 0.5 MB
  int* deg    = (int*)alloc((size_t)NNODES * 4);
  int* off    = (int*)alloc((size_t)(NNODES + 1) * 4);
  int* cur    = (int*)alloc((size_t)NNODES * 4);
  uint2* epair = (uint2*)alloc((size_t)NEDGES * 8);
  int* part   = (int*)alloc(64 * 4);

  const int nchunks = (NNODES + 1023) / 1024;  // 49

  // 1) W transpose+cvt (also zeros deg[])
  dim3 wgrid(16, 16);
  cvt_wt_kernel<<<wgrid, 256, 0, stream>>>(W, Wt, deg);

  // 2) A-slab MFMA GEMM (reads fp32 h directly): hp = bf16(bf16(h)@Wt^T + b)
  const int nmt = (NNODES + 47) / 48;  // 1042
  gemm_mfma_kernel<<<nmt * 2, 256, 0, stream>>>(h, Wt, b, hp, NNODES);

  // 3) CSR build by dst (parallel scan)
  hist_kernel<<<(NEDGES + 255) / 256, 256, 0, stream>>>(dst, deg, NEDGES);
  chunk_sum_kernel<<<nchunks, 256, 0, stream>>>(deg, part, NNODES);
  scan_part_kernel<<<1, 64, 0, stream>>>(part, nchunks);
  chunk_scan_kernel<<<nchunks, 1024, 0, stream>>>(deg, part, off, cur, NNODES);
  fill_kernel<<<(NEDGES + 255) / 256, 256, 0, stream>>>(src, dst, ew, cur,
                                                        epair, NEDGES);

  // 4) Gather + mean + relu (one wave per node)
  gather_kernel<<<(NNODES + 3) / 4, 256, 0, stream>>>(hp, off, epair, out,
                                                      NNODES);
}

// Round 14
// 137.187 us; speedup vs baseline: 1.1485x; 1.1485x over previous
//
#include <hip/hip_runtime.h>

#define NNODES 50000
#define NEDGES 200000
#define DDIM 512

typedef __attribute__((ext_vector_type(8))) short bf16x8;
typedef __attribute__((ext_vector_type(4))) float f32x4;

static __device__ __forceinline__ unsigned short f2bf(float f) {
  unsigned u = __float_as_uint(f);
  unsigned r = (u + 0x7fffu + ((u >> 16) & 1u)) >> 16;  // RNE
  return (unsigned short)r;
}

static __device__ __forceinline__ void gload_lds16(const void* g, void* l) {
  __builtin_amdgcn_global_load_lds(
      (const __attribute__((address_space(1))) unsigned int*)g,
      (__attribute__((address_space(3))) unsigned int*)l, 16, 0, 0);
}

// 8 fp32 -> bf16x8 via hardware v_cvt_pk_bf16_f32 (RNE, matches f2bf)
static __device__ __forceinline__ bf16x8 cvt_frag(f32x4 lo, f32x4 hi) {
  union { bf16x8 v; unsigned u[4]; } r;
  asm("v_cvt_pk_bf16_f32 %0, %1, %2" : "=v"(r.u[0]) : "v"(lo.x), "v"(lo.y));
  asm("v_cvt_pk_bf16_f32 %0, %1, %2" : "=v"(r.u[1]) : "v"(lo.z), "v"(lo.w));
  asm("v_cvt_pk_bf16_f32 %0, %1, %2" : "=v"(r.u[2]) : "v"(hi.x), "v"(hi.y));
  asm("v_cvt_pk_bf16_f32 %0, %1, %2" : "=v"(r.u[3]) : "v"(hi.z), "v"(hi.w));
  return r.v;
}

// ---------------------------------------------------------------------------
// Wt[n][k] = bf16(W[k][n])  (512x512 transpose via LDS) + zero deg[]
// ---------------------------------------------------------------------------
__global__ __launch_bounds__(256) void cvt_wt_kernel(
    const float* __restrict__ W, unsigned short* __restrict__ Wt,
    int* __restrict__ deg) {
  const int gid = (blockIdx.x + blockIdx.y * gridDim.x) * 256 + threadIdx.x;
  if (gid < NNODES) deg[gid] = 0;

  __shared__ float t[32][33];
  const int n0 = blockIdx.x * 32, k0 = blockIdx.y * 32;
  const int tx = threadIdx.x & 31, ty = threadIdx.x >> 5;  // ty 0..7
  for (int r = ty; r < 32; r += 8)
    t[r][tx] = W[(size_t)(k0 + r) * DDIM + n0 + tx];
  __syncthreads();
  for (int r = ty; r < 32; r += 8)
    Wt[(size_t)(n0 + r) * DDIM + k0 + tx] = f2bf(t[tx][r]);
}

// ---------------------------------------------------------------------------
// MFMA GEMM: C_bf16[M,512] = bf16(A_f32[M,512]) @ Wt_bf16[512,512]^T + bias
// Round-10 structure (best measured combined GEMM: 86us, fused fp32->bf16):
// 128x128 tile, BK=32, 4 waves (2x2), 16x16x32 MFMA.
// A staged RAW FP32 via async global_load_lds; cvt on fragment-read path
// with v_cvt_pk_bf16_f32. The ~4M "conflicts" are mostly the intrinsic 2x
// LDS-BW cost of 32B fp32 fragments (structural, not swizzle-fixable).
// B: bf16 global_load_lds, proven 0-conflict. 2-phase double buffer;
// both-sides XOR swizzles; XCD block swizzle; LDS-staged coalesced epilogue.
// ---------------------------------------------------------------------------
__global__ __launch_bounds__(256) void gemm_mfma_kernel(
    const float* __restrict__ A, const unsigned short* __restrict__ Bt,
    const float* __restrict__ bias, unsigned short* __restrict__ C, int M) {
  __shared__ float Af[2][128 * 32];          // 2 x 16 KB (fp32 A tile)
  __shared__ unsigned short Bs[2][128 * 32]; // 2 x 8 KB  (bf16 B tile)
  const int tid = threadIdx.x;
  const int wid = tid >> 6, lane = tid & 63;

  // bijective XCD-chunked remap (8 XCDs)
  const int nwg = gridDim.x;
  const int q = nwg >> 3, rr = nwg & 7;
  const int x = blockIdx.x & 7, idx = blockIdx.x >> 3;
  const int wg = x * q + min(x, rr) + idx;

  const int mt = wg >> 2, nt = wg & 3;
  const int bm = mt * 128, bn = nt * 128;
  const int wr = wid >> 1, wc = wid & 1;

  f32x4 acc[4][4] = {};

  // ---- A staging geometry: slot s = c*256 + wid*64 + lane (16B = 4 f32)
  const int lr = lane >> 3;                  // 0..7
  const int kqs = (lane & 7) ^ lr;           // swizzled source kquad
  const int ar0 = min(bm + 0 * 32 + wid * 8 + lr, M - 1);
  const int ar1 = min(bm + 1 * 32 + wid * 8 + lr, M - 1);
  const int ar2 = min(bm + 2 * 32 + wid * 8 + lr, M - 1);
  const int ar3 = min(bm + 3 * 32 + wid * 8 + lr, M - 1);
  const float* pa0 = A + (size_t)ar0 * DDIM + kqs * 4;
  const float* pa1 = A + (size_t)ar1 * DDIM + kqs * 4;
  const float* pa2 = A + (size_t)ar2 * DDIM + kqs * 4;
  const float* pa3 = A + (size_t)ar3 * DDIM + kqs * 4;

  // ---- B staging (proven 0-conflict)
  const int r0 = tid >> 2;
  const int cge = (tid & 3) ^ ((r0 >> 1) & 3);
  const unsigned short* b0 = Bt + (size_t)(bn + r0) * DDIM + cge * 8;
  const unsigned short* b1 = Bt + (size_t)(bn + r0 + 64) * DDIM + cge * 8;

  const int l16 = lane & 15, lk = lane >> 4;
  const int lke = lk ^ ((l16 >> 1) & 3);     // B swizzled read k-group
  const int s7 = l16 & 7;                    // A read-side row&7

  const int sOff0 = (wid * 64) * 8;          // B LDS bases (ushort units)
  const int sOff1 = (256 + wid * 64) * 8;

#define STAGE(buf, k0)                                   \
  do {                                                   \
    gload_lds16(pa0 + (k0), &Af[buf][wid * 256]);        \
    gload_lds16(pa1 + (k0), &Af[buf][1024 + wid * 256]); \
    gload_lds16(pa2 + (k0), &Af[buf][2048 + wid * 256]); \
    gload_lds16(pa3 + (k0), &Af[buf][3072 + wid * 256]); \
    gload_lds16(b0 + (k0), &Bs[buf][sOff0]);             \
    gload_lds16(b1 + (k0), &Bs[buf][sOff1]);             \
  } while (0)

#define COMPUTE(buf)                                                          \
  do {                                                                        \
    bf16x8 af[4], bfr[4];                                                     \
    _Pragma("unroll") for (int i = 0; i < 4; ++i) {                           \
      const int rowi = (wr * 64 + i * 16 + l16) * 32;                         \
      const f32x4 lo = *(const f32x4*)&Af[buf][rowi + (((2 * lk) ^ s7) << 2)];\
      const f32x4 hi = *(const f32x4*)&Af[buf][rowi + (((2 * lk + 1) ^ s7) << 2)]; \
      af[i] = cvt_frag(lo, hi);                                               \
      bfr[i] = *(const bf16x8*)&Bs[buf][(wc * 64 + i * 16 + l16) * 32 + lke * 8]; \
    }                                                                         \
    _Pragma("unroll") for (int i = 0; i < 4; ++i)                             \
        _Pragma("unroll") for (int j = 0; j < 4; ++j)                         \
            acc[i][j] = __builtin_amdgcn_mfma_f32_16x16x32_bf16(              \
                af[i], bfr[j], acc[i][j], 0, 0, 0);                           \
  } while (0)

  STAGE(0, 0);
  __syncthreads();
#pragma unroll 2
  for (int t = 0; t < 15; ++t) {
    const int cur = t & 1;
    STAGE(cur ^ 1, (t + 1) * 32);  // prefetch next tile into other buffer
    COMPUTE(cur);
    __syncthreads();               // drains vmcnt (prefetch) + lgkm
  }
  COMPUTE(1);       // tile 15 lives in buf 1
  __syncthreads();  // LDS about to be reused as epilogue scratch

  // ---- Epilogue: per-wave 64x64 bf16 tile staged in LDS, coalesced stores.
  unsigned short* cl = (unsigned short*)&Af[0][0] + wid * 4096;
#pragma unroll
  for (int j = 0; j < 4; ++j) {
    const float bv = bias[bn + wc * 64 + j * 16 + l16];
#pragma unroll
    for (int i = 0; i < 4; ++i)
#pragma unroll
      for (int qq = 0; qq < 4; ++qq)
        cl[(i * 16 + lk * 4 + qq) * 64 + j * 16 + l16] =
            f2bf(acc[i][j][qq] + bv);
  }
  __syncthreads();
#pragma unroll
  for (int pass = 0; pass < 8; ++pass) {
    const int rt = pass * 8 + (lane >> 3);   // row in 64x64 tile
    const int c0 = (lane & 7) * 8;           // col in 64x64 tile (8 cols/lane)
    const int grow = bm + wr * 64 + rt;
    if (grow < M) {
      const uint4 v = *(const uint4*)&cl[rt * 64 + c0];
      *(uint4*)&C[(size_t)grow * DDIM + bn + wc * 64 + c0] = v;
    }
  }
#undef STAGE
#undef COMPUTE
}

// ---------------------------------------------------------------------------
// CSR build: histogram of dst
// ---------------------------------------------------------------------------
__global__ __launch_bounds__(256) void hist_kernel(const int* __restrict__ dst,
                                                   int* __restrict__ deg, int E) {
  const int e = blockIdx.x * 256 + threadIdx.x;
  if (e < E) atomicAdd(&deg[dst[e]], 1);
}

// ---------------------------------------------------------------------------
// Parallel 3-kernel exclusive scan over deg[0..n) -> off[0..n], cur[0..n)
// ---------------------------------------------------------------------------
__global__ __launch_bounds__(256) void chunk_sum_kernel(
    const int* __restrict__ deg, int* __restrict__ part, int n) {
  const int base = blockIdx.x * 1024;
  int v = 0;
  for (int i = threadIdx.x; i < 1024; i += 256) {
    const int idx = base + i;
    v += (idx < n) ? deg[idx] : 0;
  }
#pragma unroll
  for (int s = 32; s; s >>= 1) v += __shfl_down(v, s, 64);
  __shared__ int ws[4];
  if ((threadIdx.x & 63) == 0) ws[threadIdx.x >> 6] = v;
  __syncthreads();
  if (threadIdx.x == 0) part[blockIdx.x] = ws[0] + ws[1] + ws[2] + ws[3];
}

__global__ void scan_part_kernel(int* __restrict__ part, int nb) {
  const int lane = threadIdx.x & 63;
  int v = (lane < nb) ? part[lane] : 0;
  int incl = v;
#pragma unroll
  for (int s = 1; s < 64; s <<= 1) {
    int t = __shfl_up(incl, s, 64);
    if (lane >= s) incl += t;
  }
  if (lane < nb) part[lane] = incl - v;  // exclusive
}

__global__ __launch_bounds__(1024) void chunk_scan_kernel(
    const int* __restrict__ deg, const int* __restrict__ part,
    int* __restrict__ off, int* __restrict__ cur, int n) {
  __shared__ int wsum[16];
  const int tid = threadIdx.x, lane = tid & 63, wid = tid >> 6;
  const int i = blockIdx.x * 1024 + tid;
  const int v = (i < n) ? deg[i] : 0;
  int incl = v;
#pragma unroll
  for (int s = 1; s < 64; s <<= 1) {
    int t = __shfl_up(incl, s, 64);
    if (lane >= s) incl += t;
  }
  if (lane == 63) wsum[wid] = incl;
  __syncthreads();
  if (wid == 0 && lane < 16) {
    int wv = wsum[lane];
#pragma unroll
    for (int s = 1; s < 16; s <<= 1) {
      int t = __shfl_up(wv, s, 16);
      if (lane >= s) wv += t;
    }
    wsum[lane] = wv;
  }
  __syncthreads();
  const int add = part[blockIdx.x] + ((wid > 0) ? wsum[wid - 1] : 0);
  if (i < n) {
    off[i + 1] = add + incl;
    cur[i] = add + incl - v;
  }
  if (i == 0) off[0] = 0;
}

// ---------------------------------------------------------------------------
// CSR fill: slot per edge via per-dst cursor; pack (src, weight) as uint2.
// ---------------------------------------------------------------------------
__global__ __launch_bounds__(256) void fill_kernel(
    const int* __restrict__ src, const int* __restrict__ dst,
    const float* __restrict__ ew, int* __restrict__ cur,
    uint2* __restrict__ epair, int E) {
  const int e = blockIdx.x * 256 + threadIdx.x;
  if (e >= E) return;
  const int p = atomicAdd(&cur[dst[e]], 1);
  epair[p] = make_uint2((unsigned)src[e], __float_as_uint(ew[e]));
}

// ---------------------------------------------------------------------------
// Gather: one wave per node; 4-deep edge unroll; mean + relu; nontemporal
// row write (out is write-once — keep hp resident in L2/L3).
// ---------------------------------------------------------------------------
__global__ __launch_bounds__(256) void gather_kernel(
    const unsigned short* __restrict__ hp, const int* __restrict__ off,
    const uint2* __restrict__ epair, float* __restrict__ out, int n) {
  const int node = blockIdx.x * 4 + (threadIdx.x >> 6);
  if (node >= n) return;
  const int lane = threadIdx.x & 63;
  const int beg = off[node], end = off[node + 1];

  float acc[8] = {0.f, 0.f, 0.f, 0.f, 0.f, 0.f, 0.f, 0.f};
  int p = beg;
  for (; p + 4 <= end; p += 4) {
    uint2 e[4];
    uint4 u[4];
#pragma unroll
    for (int m = 0; m < 4; ++m) e[m] = epair[p + m];
#pragma unroll
    for (int m = 0; m < 4; ++m)
      u[m] = *(const uint4*)(hp + (size_t)e[m].x * DDIM + lane * 8);
#pragma unroll
    for (int m = 0; m < 4; ++m) {
      const float w = __uint_as_float(e[m].y);
      const unsigned a[4] = {u[m].x, u[m].y, u[m].z, u[m].w};
#pragma unroll
      for (int qv = 0; qv < 4; ++qv) {
        acc[2 * qv + 0] += w * __uint_as_float(a[qv] << 16);
        acc[2 * qv + 1] += w * __uint_as_float(a[qv] & 0xffff0000u);
      }
    }
  }
  for (; p < end; ++p) {
    const uint2 e0 = epair[p];
    const float w0 = __uint_as_float(e0.y);
    const uint4 u0 = *(const uint4*)(hp + (size_t)e0.x * DDIM + lane * 8);
    const unsigned a0[4] = {u0.x, u0.y, u0.z, u0.w};
#pragma unroll
    for (int qv = 0; qv < 4; ++qv) {
      acc[2 * qv + 0] += w0 * __uint_as_float(a0[qv] << 16);
      acc[2 * qv + 1] += w0 * __uint_as_float(a0[qv] & 0xffff0000u);
    }
  }

  const float inv = 1.0f / fmaxf((float)(end - beg), 1.0f);
  f32x4 o0, o1;
  o0.x = fmaxf(acc[0] * inv, 0.f);
  o0.y = fmaxf(acc[1] * inv, 0.f);
  o0.z = fmaxf(acc[2] * inv, 0.f);
  o0.w = fmaxf(acc[3] * inv, 0.f);
  o1.x = fmaxf(acc[4] * inv, 0.f);
  o1.y = fmaxf(acc[5] * inv, 0.f);
  o1.z = fmaxf(acc[6] * inv, 0.f);
  o1.w = fmaxf(acc[7] * inv, 0.f);
  float* orow = out + (size_t)node * DDIM + lane * 8;
  __builtin_nontemporal_store(o0, (f32x4*)(orow + 0));
  __builtin_nontemporal_store(o1, (f32x4*)(orow + 4));
}

extern "C" void kernel_launch(void* const* d_in, const int* in_sizes, int n_in,
                              void* d_out, int out_size, void* d_ws, size_t ws_size,
                              hipStream_t stream) {
  const float* h  = (const float*)d_in[0];
  const float* W  = (const float*)d_in[1];
  const float* b  = (const float*)d_in[2];
  const float* ew = (const float*)d_in[3];
  const int* src  = (const int*)d_in[4];
  const int* dst  = (const int*)d_in[5];
  float* out = (float*)d_out;

  // Workspace: hp (bf16 h_proj), Wt, CSR arrays
  char* ws = (char*)d_ws;
  size_t o = 0;
  auto alloc = [&](size_t bytes) {
    char* p = ws + o;
    o += (bytes + 255) & ~(size_t)255;
    return p;
  };
  unsigned short* hp = (unsigned short*)alloc((size_t)NNODES * DDIM * 2);  // 51.2 MB
  unsigned short* Wt = (unsigned short*)alloc((size_t)DDIM * DDIM * 2);    // 0.5 MB
  int* deg    = (int*)alloc((size_t)NNODES * 4);
  int* off    = (int*)alloc((size_t)(NNODES + 1) * 4);
  int* cur    = (int*)alloc((size_t)NNODES * 4);
  uint2* epair = (uint2*)alloc((size_t)NEDGES * 8);
  int* part   = (int*)alloc(64 * 4);

  const int nchunks = (NNODES + 1023) / 1024;  // 49

  // 1) W transpose+cvt (also zeros deg[])
  dim3 wgrid(16, 16);
  cvt_wt_kernel<<<wgrid, 256, 0, stream>>>(W, Wt, deg);

  // 2) MFMA GEMM (reads fp32 h directly): hp = bf16(bf16(h) @ Wt^T + b)
  const int mtiles = (NNODES + 127) / 128;  // 391
  gemm_mfma_kernel<<<mtiles * 4, 256, 0, stream>>>(h, Wt, b, hp, NNODES);

  // 3) CSR build by dst (parallel scan)
  hist_kernel<<<(NEDGES + 255) / 256, 256, 0, stream>>>(dst, deg, NEDGES);
  chunk_sum_kernel<<<nchunks, 256, 0, stream>>>(deg, part, NNODES);
  scan_part_kernel<<<1, 64, 0, stream>>>(part, nchunks);
  chunk_scan_kernel<<<nchunks, 1024, 0, stream>>>(deg, part, off, cur, NNODES);
  fill_kernel<<<(NEDGES + 255) / 256, 256, 0, stream>>>(src, dst, ew, cur,
                                                        epair, NEDGES);

  // 4) Gather + mean + relu (one wave per node)
  gather_kernel<<<(NNODES + 3) / 4, 256, 0, stream>>>(hp, off, epair, out,
                                                      NNODES);
}